// Round 3
// baseline (438.754 us; speedup 1.0000x reference)
//
#include <hip/hip_runtime.h>
#include <stdint.h>

#define Bv 16
#define Sv 512
#define Hv 12
#define Dv 64
#define HIDv 768

typedef __attribute__((ext_vector_type(8))) short bf8_t;
typedef __attribute__((ext_vector_type(4))) float f32x4;
typedef __attribute__((ext_vector_type(8))) unsigned short u16x8;
typedef __attribute__((ext_vector_type(4))) unsigned short u16x4;

__device__ __forceinline__ float b2f(unsigned short u){
    union { unsigned int i; float f; } x; x.i = ((unsigned int)u) << 16; return x.f;
}
__device__ __forceinline__ unsigned short f2b(float f){
    union { float f; unsigned int i; } x; x.f = f;
    unsigned int r = x.i + 0x7fff + ((x.i >> 16) & 1);
    return (unsigned short)(r >> 16);
}

#define RS 0.18033688f          /* 0.125 * log2(e) */
#define LOG2E 1.44269504f

// ---------------------------------------------------------------------------
__global__ void cvt_bf16(const float* __restrict__ src, unsigned short* __restrict__ dst, int n4){
    int i = blockIdx.x * 256 + threadIdx.x;
    int stride = gridDim.x * 256;
    for (; i < n4; i += stride){
        float4 v = ((const float4*)src)[i];
        u16x4 o = { f2b(v.x), f2b(v.y), f2b(v.z), f2b(v.w) };
        ((u16x4*)dst)[i] = o;
    }
}

__global__ void cvt_w3(const float* __restrict__ a, const float* __restrict__ b,
                       const float* __restrict__ c, unsigned short* __restrict__ dst, int n4each){
    int i = blockIdx.x * 256 + threadIdx.x;
    if (i >= 3*n4each) return;
    int which = i / n4each, j = i - which*n4each;
    const float* src = which == 0 ? a : (which == 1 ? b : c);
    float4 v = ((const float4*)src)[j];
    u16x4 o = { f2b(v.x), f2b(v.y), f2b(v.z), f2b(v.w) };
    ((u16x4*)dst)[i] = o;
}

// ---------------------------------------------------------------------------
// lvl[b][l][r] = (0.5*ce[c]+0.5*we[w])*RS + mask[b][r]*LOG2E   (bf16)
// ---------------------------------------------------------------------------
__global__ __launch_bounds__(256) void prep_bias(
    const int* __restrict__ cmat, const int* __restrict__ wmat,
    const float* __restrict__ mask, const float* __restrict__ ce, const float* __restrict__ we,
    unsigned short* __restrict__ lvlb)
{
    __shared__ float tab[64];
    const int t = threadIdx.x;
    if (t < 64) tab[t] = (0.5f*ce[t>>3] + 0.5f*we[t&7]) * RS;
    __syncthreads();
    const size_t row = blockIdx.x;            // b*512 + l
    const int b = (int)(row >> 9);
    const size_t base = row * 512;
    int2 c2 = *(const int2*)(cmat + base + t*2);
    int2 w2 = *(const int2*)(wmat + base + t*2);
    float2 m2 = *(const float2*)(mask + (size_t)b*512 + t*2);
    unsigned short o0 = f2b(tab[(c2.x<<3)|w2.x] + m2.x * LOG2E);
    unsigned short o1 = f2b(tab[(c2.y<<3)|w2.y] + m2.y * LOG2E);
    *(unsigned int*)(lvlb + base + t*2) = (unsigned)o0 | ((unsigned)o1 << 16);
}

// ---------------------------------------------------------------------------
// QKV projection (unchanged from R2): Q,K -> [proj][b][h][s][d], V -> [b][h][d][s]
// ---------------------------------------------------------------------------
__global__ __launch_bounds__(256,3) void qkv_gemm(
    const unsigned short* __restrict__ Xb,
    const unsigned short* __restrict__ Wb,
    const float* __restrict__ bq, const float* __restrict__ bk, const float* __restrict__ bv,
    unsigned short* __restrict__ qkb,
    unsigned short* __restrict__ vtb)
{
    __shared__ unsigned short Ab[128*40];
    __shared__ unsigned short Bb[128*40];
    const int t = threadIdx.x;
    const int w = t >> 6, lane = t & 63, g = lane >> 4, cc = lane & 15;
    const int wm = w >> 1, wn = w & 1;
    const int m0 = blockIdx.x * 128;
    const int n0 = blockIdx.y * 128;

    const f32x4 fz = {0.f,0.f,0.f,0.f};
    f32x4 acc[4][4];
    #pragma unroll
    for (int i = 0; i < 4; ++i)
        #pragma unroll
        for (int j = 0; j < 4; ++j) acc[i][j] = fz;

    u16x8 pa[2], pb[2];
    #pragma unroll
    for (int r = 0; r < 2; ++r){
        int chunk = t + r*256; int row = chunk >> 2; int ch = chunk & 3;
        pa[r] = *(const u16x8*)(Xb + (size_t)(m0+row)*768 + ch*8);
        pb[r] = *(const u16x8*)(Wb + (size_t)(n0+row)*768 + ch*8);
    }
    for (int k0 = 0; k0 < 768; k0 += 32){
        __syncthreads();
        #pragma unroll
        for (int r = 0; r < 2; ++r){
            int chunk = t + r*256; int row = chunk >> 2; int ch = chunk & 3;
            *(u16x8*)&Ab[row*40 + ch*8] = pa[r];
            *(u16x8*)&Bb[row*40 + ch*8] = pb[r];
        }
        __syncthreads();
        if (k0 + 32 < 768){
            #pragma unroll
            for (int r = 0; r < 2; ++r){
                int chunk = t + r*256; int row = chunk >> 2; int ch = chunk & 3;
                pa[r] = *(const u16x8*)(Xb + (size_t)(m0+row)*768 + (k0+32) + ch*8);
                pb[r] = *(const u16x8*)(Wb + (size_t)(n0+row)*768 + (k0+32) + ch*8);
            }
        }
        bf8_t af[4], bfr[4];
        #pragma unroll
        for (int mf = 0; mf < 4; ++mf)
            af[mf] = *(const bf8_t*)&Ab[(wm*64 + mf*16 + cc)*40 + g*8];
        #pragma unroll
        for (int nf = 0; nf < 4; ++nf)
            bfr[nf] = *(const bf8_t*)&Bb[(wn*64 + nf*16 + cc)*40 + g*8];
        #pragma unroll
        for (int mf = 0; mf < 4; ++mf)
            #pragma unroll
            for (int nf = 0; nf < 4; ++nf)
                acc[mf][nf] = __builtin_amdgcn_mfma_f32_16x16x32_bf16(af[mf], bfr[nf], acc[mf][nf], 0,0,0);
    }

    const int b  = m0 >> 9;
    const int s0 = (m0 & 511) + wm*64;
    const int nbase = n0 + wn*64;
    const int proj = nbase / 768;
    const int nin0 = nbase % 768;
    const float* bias = proj == 0 ? bq : (proj == 1 ? bk : bv);
    #pragma unroll
    for (int nf = 0; nf < 4; ++nf){
        int nin = nin0 + nf*16 + cc;
        int h = nin >> 6, d = nin & 63;
        float bvv = bias[nin];
        #pragma unroll
        for (int mf = 0; mf < 4; ++mf){
            int s = s0 + mf*16 + g*4;
            if (proj < 2){
                unsigned short* base = qkb + (((((size_t)proj*Bv + b)*Hv + h)*Sv + s)*Dv + d);
                #pragma unroll
                for (int r2 = 0; r2 < 4; ++r2)
                    base[(size_t)r2*Dv] = f2b(acc[mf][nf][r2] + bvv);
            } else {
                u16x4 o = { f2b(acc[mf][nf][0]+bvv), f2b(acc[mf][nf][1]+bvv),
                            f2b(acc[mf][nf][2]+bvv), f2b(acc[mf][nf][3]+bvv) };
                *(u16x4*)(vtb + ((((size_t)b*Hv + h)*Dv + d)*Sv + s)) = o;
            }
        }
    }
}

// ---------------------------------------------------------------------------
// Fused attention v3: 3 blocks/CU (49.7KB LDS), register prefetch (T14),
// compact band storage for T1/T2, exp2-domain softmax, setprio.
// ---------------------------------------------------------------------------
__global__ __launch_bounds__(256,3) void attn(
    const unsigned short* __restrict__ qkb,
    const unsigned short* __restrict__ vtb,
    const unsigned short* __restrict__ deb,    // [1023][64] bf16
    const unsigned short* __restrict__ lvlb,   // [16][512][512] bf16, prescaled
    float* __restrict__ out)
{
    __shared__ __align__(16) unsigned short sm[24832];
    unsigned short* ks  = sm;            // [64][64] swz
    unsigned short* vsq = sm + 4096;     // [64][64] swz (Q in prologue, then V)
    unsigned short* des = sm + 8192;     // [128][64] swz; P alias [64][72]
    unsigned short* t1c = sm + 16384;    // [64][66]  t1c[ll][rl]
    unsigned short* t2c = sm + 20608;    // [64][66]  t2c[rl][ll]

    const int t = threadIdx.x, w = t >> 6, lane = t & 63, g = lane >> 4, cc = lane & 15;
    const int srow = t >> 3, sch = t & 7;         // staging row/col8

    const int wg = blockIdx.x;
    const int xcd = wg & 7, inner = wg >> 3, lt = inner & 7, gg = inner >> 3;
    const int bh = gg * 8 + xcd;
    const int b = bh / Hv, h = bh % Hv;
    const int l0 = lt * 64;

    const unsigned short* qp = qkb + ((((size_t)0*Bv + b)*Hv + h)*Sv + l0)*Dv;
    const unsigned short* kp = qkb + ((((size_t)1*Bv + b)*Hv + h)*Sv)*Dv;
    const unsigned short* vp = vtb + (((size_t)b*Hv + h)*Dv)*Sv;
    const unsigned short* lvp = lvlb + ((size_t)b*Sv + l0)*Sv;

    const f32x4 fz = {0.f,0.f,0.f,0.f};
    const int llb = w*16 + g*4;

    u16x8 pk[2], pd[4], pv[2];

    // ---- prologue: Q -> vsq, prefetch chunk 0 ----
    #pragma unroll
    for (int r = 0; r < 2; ++r){
        int row = srow + 32*r;
        u16x8 v = *(const u16x8*)(qp + (size_t)row*64 + sch*8);
        *(u16x8*)&vsq[row*64 + ((sch ^ (row & 7))*8)] = v;
    }
    #pragma unroll
    for (int r = 0; r < 2; ++r){
        int row = srow + 32*r;
        pk[r] = *(const u16x8*)(kp + (size_t)row*64 + sch*8);
    }
    {
        const int base = l0 + 448;
        #pragma unroll
        for (int r = 0; r < 4; ++r){
            int row = srow + 32*r;
            int gr = base + row; if (gr > 1022) gr = 1022;
            pd[r] = *(const u16x8*)(deb + (size_t)gr*64 + sch*8);
        }
    }
    __syncthreads();                                // Q visible
    bf8_t qf0, qf1;
    {
        int row = w*16 + cc;
        qf0 = *(const bf8_t*)&vsq[row*64 + ((g       ^ (row & 7))*8)];
        qf1 = *(const bf8_t*)&vsq[row*64 + (((g + 4) ^ (row & 7))*8)];
    }
    #pragma unroll
    for (int r = 0; r < 2; ++r){
        int row = srow + 32*r;
        pv[r] = *(const u16x8*)(vp + (size_t)row*512 + sch*8);
    }
    #pragma unroll
    for (int r = 0; r < 2; ++r){
        int row = srow + 32*r;
        *(u16x8*)&ks[row*64 + ((sch ^ (row & 7))*8)] = pk[r];
    }
    #pragma unroll
    for (int r = 0; r < 4; ++r){
        int row = srow + 32*r;
        *(u16x8*)&des[row*64 + ((sch ^ (row & 7))*8)] = pd[r];
    }
    __syncthreads();                                // qf reads done; ks/des visible
    #pragma unroll
    for (int r = 0; r < 2; ++r){
        int row = srow + 32*r;
        *(u16x8*)&vsq[row*64 + ((sch ^ (row & 7))*8)] = pv[r];
    }
    __syncthreads();                                // all chunk-0 tiles ready

    float m_run[4] = {-1e30f,-1e30f,-1e30f,-1e30f};
    float l_run[4] = {0.f,0.f,0.f,0.f};
    f32x4 ctx[4] = {fz,fz,fz,fz};

    for (int c8 = 0; c8 < 8; ++c8){
        const int r0 = c8 * 64;
        // ---- prefetch next chunk (regs only) + current lvl tile ----
        if (c8 < 7){
            const int r0n = r0 + 64;
            #pragma unroll
            for (int r = 0; r < 2; ++r){
                int row = srow + 32*r;
                pk[r] = *(const u16x8*)(kp + (size_t)(r0n+row)*64 + sch*8);
            }
            const int base = l0 - r0n + 448;
            #pragma unroll
            for (int r = 0; r < 4; ++r){
                int row = srow + 32*r;
                int gr = base + row; if (gr > 1022) gr = 1022;
                pd[r] = *(const u16x8*)(deb + (size_t)gr*64 + sch*8);
            }
            #pragma unroll
            for (int r = 0; r < 2; ++r){
                int row = srow + 32*r;
                pv[r] = *(const u16x8*)(vp + (size_t)row*512 + r0n + sch*8);
            }
        }
        unsigned short lv[4][4];
        #pragma unroll
        for (int i = 0; i < 4; ++i){
            int rl = ((w + i) & 3)*16 + cc;
            #pragma unroll
            for (int reg = 0; reg < 4; ++reg)
                lv[reg][i] = lvp[(size_t)(llb + reg)*512 + r0 + rl];
        }

        // ---- MFMA phase ----
        __builtin_amdgcn_s_setprio(1);
        f32x4 accs[4];
        bf8_t kf0, kf1;
        #pragma unroll
        for (int i = 0; i < 4; ++i){                    // S = Q K^T (nf = (w+i)&3)
            int row = ((w + i) & 3)*16 + cc;
            bf8_t b0 = *(const bf8_t*)&ks[row*64 + ((g       ^ (row & 7))*8)];
            bf8_t b1 = *(const bf8_t*)&ks[row*64 + (((g + 4) ^ (row & 7))*8)];
            if (i == 0){ kf0 = b0; kf1 = b1; }
            f32x4 a = fz;
            a = __builtin_amdgcn_mfma_f32_16x16x32_bf16(qf0, b0, a, 0,0,0);
            a = __builtin_amdgcn_mfma_f32_16x16x32_bf16(qf1, b1, a, 0,0,0);
            accs[i] = a;
        }
        #pragma unroll
        for (int i = 0; i < 5; ++i){                    // T1 = Q DE^T, compact store
            int jb = (w + i)*16 + cc;
            bf8_t d0 = *(const bf8_t*)&des[jb*64 + ((g       ^ (jb & 7))*8)];
            bf8_t d1 = *(const bf8_t*)&des[jb*64 + (((g + 4) ^ (jb & 7))*8)];
            f32x4 a = fz;
            a = __builtin_amdgcn_mfma_f32_16x16x32_bf16(qf0, d0, a, 0,0,0);
            a = __builtin_amdgcn_mfma_f32_16x16x32_bf16(qf1, d1, a, 0,0,0);
            #pragma unroll
            for (int reg = 0; reg < 4; ++reg){
                int ll = llb + reg;
                int rl = ll + 63 - jb;
                if (rl >= 0 && rl < 64) t1c[ll*66 + rl] = f2b(a[reg]);
            }
        }
        #pragma unroll
        for (int i = 0; i < 5; ++i){                    // T2 = K DE^T, compact store
            int jb = (3 - w + i)*16 + cc;
            bf8_t d0 = *(const bf8_t*)&des[jb*64 + ((g       ^ (jb & 7))*8)];
            bf8_t d1 = *(const bf8_t*)&des[jb*64 + (((g + 4) ^ (jb & 7))*8)];
            f32x4 a = fz;
            a = __builtin_amdgcn_mfma_f32_16x16x32_bf16(kf0, d0, a, 0,0,0);
            a = __builtin_amdgcn_mfma_f32_16x16x32_bf16(kf1, d1, a, 0,0,0);
            #pragma unroll
            for (int reg = 0; reg < 4; ++reg){
                int rl = llb + reg;
                int ll = rl + jb - 63;
                if (ll >= 0 && ll < 64) t2c[rl*66 + ll] = f2b(a[reg]);
            }
        }
        __builtin_amdgcn_s_setprio(0);
        __syncthreads();                                // B3: t1c/t2c visible

        // ---- epilogue: combine + online softmax (exp2 domain) ----
        float sv[4][4];                                 // [reg][i]
        #pragma unroll
        for (int i = 0; i < 4; ++i){
            int rl = ((w + i) & 3)*16 + cc;
            #pragma unroll
            for (int reg = 0; reg < 4; ++reg){
                int ll = llb + reg;
                float t1v = b2f(t1c[ll*66 + rl]);
                float t2v = b2f(t2c[rl*66 + ll]);
                sv[reg][i] = (accs[i][reg] + t1v + t2v) * RS + b2f(lv[reg][i]);
            }
        }
        unsigned short* P = des;                        // alias [64][72]
        #pragma unroll
        for (int reg = 0; reg < 4; ++reg){
            float rmax = fmaxf(fmaxf(sv[reg][0], sv[reg][1]), fmaxf(sv[reg][2], sv[reg][3]));
            rmax = fmaxf(rmax, __shfl_xor(rmax, 1));
            rmax = fmaxf(rmax, __shfl_xor(rmax, 2));
            rmax = fmaxf(rmax, __shfl_xor(rmax, 4));
            rmax = fmaxf(rmax, __shfl_xor(rmax, 8));
            float mnew = fmaxf(m_run[reg], rmax);
            float resc = __builtin_amdgcn_exp2f(m_run[reg] - mnew);
            float ps = 0.f;
            int ll = llb + reg;
            #pragma unroll
            for (int i = 0; i < 4; ++i){
                int rl = ((w + i) & 3)*16 + cc;
                float p = __builtin_amdgcn_exp2f(sv[reg][i] - mnew);
                ps += p;
                P[ll*72 + rl] = f2b(p);
            }
            ps += __shfl_xor(ps, 1); ps += __shfl_xor(ps, 2);
            ps += __shfl_xor(ps, 4); ps += __shfl_xor(ps, 8);
            l_run[reg] = l_run[reg]*resc + ps;
            m_run[reg] = mnew;
            ctx[0][reg] *= resc; ctx[1][reg] *= resc;
            ctx[2][reg] *= resc; ctx[3][reg] *= resc;
        }

        // ---- PV ----
        __builtin_amdgcn_s_setprio(1);
        #pragma unroll
        for (int kh = 0; kh < 2; ++kh){
            int prow = w*16 + cc;
            bf8_t pf = *(const bf8_t*)&P[prow*72 + g*8 + kh*32];
            #pragma unroll
            for (int nf = 0; nf < 4; ++nf){
                int vr = nf*16 + cc;
                bf8_t vf = *(const bf8_t*)&vsq[vr*64 + (((g + 4*kh) ^ (vr & 7))*8)];
                ctx[nf] = __builtin_amdgcn_mfma_f32_16x16x32_bf16(pf, vf, ctx[nf], 0,0,0);
            }
        }
        __builtin_amdgcn_s_setprio(0);

        if (c8 < 7){
            __syncthreads();                            // B1: all LDS reads done
            #pragma unroll
            for (int r = 0; r < 2; ++r){
                int row = srow + 32*r;
                *(u16x8*)&ks[row*64 + ((sch ^ (row & 7))*8)] = pk[r];
            }
            #pragma unroll
            for (int r = 0; r < 4; ++r){
                int row = srow + 32*r;
                *(u16x8*)&des[row*64 + ((sch ^ (row & 7))*8)] = pd[r];
            }
            #pragma unroll
            for (int r = 0; r < 2; ++r){
                int row = srow + 32*r;
                *(u16x8*)&vsq[row*64 + ((sch ^ (row & 7))*8)] = pv[r];
            }
            __syncthreads();                            // B2: next tiles ready
        }
    }

    #pragma unroll
    for (int nf = 0; nf < 4; ++nf){
        #pragma unroll
        for (int reg = 0; reg < 4; ++reg){
            int ll = llb + reg;
            out[((size_t)b*Sv + l0 + ll)*HIDv + h*64 + nf*16 + cc] = ctx[nf][reg] / l_run[reg];
        }
    }
}

extern "C" void kernel_launch(void* const* d_in, const int* in_sizes, int n_in,
                              void* d_out, int out_size, void* d_ws, size_t ws_size,
                              hipStream_t stream)
{
    const float* hs   = (const float*)d_in[0];
    const float* mask = (const float*)d_in[1];
    const int*   cmat = (const int*)  d_in[2];
    const int*   wmat = (const int*)  d_in[3];
    const float* Wq   = (const float*)d_in[4];
    const float* bq   = (const float*)d_in[5];
    const float* Wk   = (const float*)d_in[6];
    const float* bk   = (const float*)d_in[7];
    const float* Wv   = (const float*)d_in[8];
    const float* bv   = (const float*)d_in[9];
    const float* de   = (const float*)d_in[10];
    const float* ce   = (const float*)d_in[11];
    const float* we   = (const float*)d_in[12];
    float* out = (float*)d_out;

    unsigned short* Xb   = (unsigned short*)d_ws;        // 8192*768
    unsigned short* Wb   = Xb   + 6291456;               // 2304*768
    unsigned short* deb  = Wb   + 1769472;               // 1023*64 (padded)
    unsigned short* qkb  = deb  + 65536;                 // 2*16*12*512*64
    unsigned short* vtb  = qkb  + 12582912;              // 16*12*64*512
    unsigned short* lvlb = vtb  + 6291456;               // 16*512*512

    cvt_bf16<<<2048, 256, 0, stream>>>(hs, Xb, 1572864);
    cvt_w3<<<1728, 256, 0, stream>>>(Wq, Wk, Wv, Wb, 147456);
    cvt_bf16<<<64,   256, 0, stream>>>(de, deb, 16368);
    prep_bias<<<8192, 256, 0, stream>>>(cmat, wmat, mask, ce, we, lvlb);

    qkv_gemm<<<dim3(64, 18), 256, 0, stream>>>(Xb, Wb, bq, bk, bv, qkb, vtb);
    attn<<<1536, 256, 0, stream>>>(qkb, vtb, deb, lvlb, out);
}

// Round 4
// 302.016 us; speedup vs baseline: 1.4528x; 1.4528x over previous
//
#include <hip/hip_runtime.h>
#include <stdint.h>

#define Bv 16
#define Sv 512
#define Hv 12
#define Dv 64
#define HIDv 768

typedef __attribute__((ext_vector_type(8))) short bf8_t;
typedef __attribute__((ext_vector_type(4))) float f32x4;
typedef __attribute__((ext_vector_type(8))) unsigned short u16x8;
typedef __attribute__((ext_vector_type(4))) unsigned short u16x4;

__device__ __forceinline__ float b2f(unsigned short u){
    union { unsigned int i; float f; } x; x.i = ((unsigned int)u) << 16; return x.f;
}
__device__ __forceinline__ unsigned short f2b(float f){
    union { float f; unsigned int i; } x; x.f = f;
    unsigned int r = x.i + 0x7fff + ((x.i >> 16) & 1);
    return (unsigned short)(r >> 16);
}
__device__ __forceinline__ void gload16(const unsigned short* g, unsigned short* l){
    __builtin_amdgcn_global_load_lds(
        (const __attribute__((address_space(1))) void*)g,
        (__attribute__((address_space(3))) void*)l, 16, 0, 0);
}

#define RS 0.18033688f          /* 0.125 * log2(e) */
#define LOG2E 1.44269504f

// ---------------------------------------------------------------------------
__global__ void cvt_bf16(const float* __restrict__ src, unsigned short* __restrict__ dst, int n4){
    int i = blockIdx.x * 256 + threadIdx.x;
    int stride = gridDim.x * 256;
    for (; i < n4; i += stride){
        float4 v = ((const float4*)src)[i];
        u16x4 o = { f2b(v.x), f2b(v.y), f2b(v.z), f2b(v.w) };
        ((u16x4*)dst)[i] = o;
    }
}

__global__ void cvt_w3(const float* __restrict__ a, const float* __restrict__ b,
                       const float* __restrict__ c, unsigned short* __restrict__ dst, int n4each){
    int i = blockIdx.x * 256 + threadIdx.x;
    if (i >= 3*n4each) return;
    int which = i / n4each, j = i - which*n4each;
    const float* src = which == 0 ? a : (which == 1 ? b : c);
    float4 v = ((const float4*)src)[j];
    u16x4 o = { f2b(v.x), f2b(v.y), f2b(v.z), f2b(v.w) };
    ((u16x4*)dst)[i] = o;
}

// ---------------------------------------------------------------------------
// lvl[b][l][r] = (0.5*ce[c]+0.5*we[w])*RS + mask[b][r]*LOG2E   (bf16)
// ---------------------------------------------------------------------------
__global__ __launch_bounds__(256) void prep_bias(
    const int* __restrict__ cmat, const int* __restrict__ wmat,
    const float* __restrict__ mask, const float* __restrict__ ce, const float* __restrict__ we,
    unsigned short* __restrict__ lvlb)
{
    __shared__ float tab[64];
    const int t = threadIdx.x;
    if (t < 64) tab[t] = (0.5f*ce[t>>3] + 0.5f*we[t&7]) * RS;
    __syncthreads();
    const size_t row = blockIdx.x;            // b*512 + l
    const int b = (int)(row >> 9);
    const size_t base = row * 512;
    int2 c2 = *(const int2*)(cmat + base + t*2);
    int2 w2 = *(const int2*)(wmat + base + t*2);
    float2 m2 = *(const float2*)(mask + (size_t)b*512 + t*2);
    unsigned short o0 = f2b(tab[(c2.x<<3)|w2.x] + m2.x * LOG2E);
    unsigned short o1 = f2b(tab[(c2.y<<3)|w2.y] + m2.y * LOG2E);
    *(unsigned int*)(lvlb + base + t*2) = (unsigned)o0 | ((unsigned)o1 << 16);
}

// ---------------------------------------------------------------------------
// QKV projection (verified): Q,K -> [proj][b][h][s][d], V -> [b][h][d][s]
// ---------------------------------------------------------------------------
__global__ __launch_bounds__(256,3) void qkv_gemm(
    const unsigned short* __restrict__ Xb,
    const unsigned short* __restrict__ Wb,
    const float* __restrict__ bq, const float* __restrict__ bk, const float* __restrict__ bv,
    unsigned short* __restrict__ qkb,
    unsigned short* __restrict__ vtb)
{
    __shared__ unsigned short Ab[128*40];
    __shared__ unsigned short Bb[128*40];
    const int t = threadIdx.x;
    const int w = t >> 6, lane = t & 63, g = lane >> 4, cc = lane & 15;
    const int wm = w >> 1, wn = w & 1;
    const int m0 = blockIdx.x * 128;
    const int n0 = blockIdx.y * 128;

    const f32x4 fz = {0.f,0.f,0.f,0.f};
    f32x4 acc[4][4];
    #pragma unroll
    for (int i = 0; i < 4; ++i)
        #pragma unroll
        for (int j = 0; j < 4; ++j) acc[i][j] = fz;

    u16x8 pa[2], pb[2];
    #pragma unroll
    for (int r = 0; r < 2; ++r){
        int chunk = t + r*256; int row = chunk >> 2; int ch = chunk & 3;
        pa[r] = *(const u16x8*)(Xb + (size_t)(m0+row)*768 + ch*8);
        pb[r] = *(const u16x8*)(Wb + (size_t)(n0+row)*768 + ch*8);
    }
    for (int k0 = 0; k0 < 768; k0 += 32){
        __syncthreads();
        #pragma unroll
        for (int r = 0; r < 2; ++r){
            int chunk = t + r*256; int row = chunk >> 2; int ch = chunk & 3;
            *(u16x8*)&Ab[row*40 + ch*8] = pa[r];
            *(u16x8*)&Bb[row*40 + ch*8] = pb[r];
        }
        __syncthreads();
        if (k0 + 32 < 768){
            #pragma unroll
            for (int r = 0; r < 2; ++r){
                int chunk = t + r*256; int row = chunk >> 2; int ch = chunk & 3;
                pa[r] = *(const u16x8*)(Xb + (size_t)(m0+row)*768 + (k0+32) + ch*8);
                pb[r] = *(const u16x8*)(Wb + (size_t)(n0+row)*768 + (k0+32) + ch*8);
            }
        }
        bf8_t af[4], bfr[4];
        #pragma unroll
        for (int mf = 0; mf < 4; ++mf)
            af[mf] = *(const bf8_t*)&Ab[(wm*64 + mf*16 + cc)*40 + g*8];
        #pragma unroll
        for (int nf = 0; nf < 4; ++nf)
            bfr[nf] = *(const bf8_t*)&Bb[(wn*64 + nf*16 + cc)*40 + g*8];
        #pragma unroll
        for (int mf = 0; mf < 4; ++mf)
            #pragma unroll
            for (int nf = 0; nf < 4; ++nf)
                acc[mf][nf] = __builtin_amdgcn_mfma_f32_16x16x32_bf16(af[mf], bfr[nf], acc[mf][nf], 0,0,0);
    }

    const int b  = m0 >> 9;
    const int s0 = (m0 & 511) + wm*64;
    const int nbase = n0 + wn*64;
    const int proj = nbase / 768;
    const int nin0 = nbase % 768;
    const float* bias = proj == 0 ? bq : (proj == 1 ? bk : bv);
    #pragma unroll
    for (int nf = 0; nf < 4; ++nf){
        int nin = nin0 + nf*16 + cc;
        int h = nin >> 6, d = nin & 63;
        float bvv = bias[nin];
        #pragma unroll
        for (int mf = 0; mf < 4; ++mf){
            int s = s0 + mf*16 + g*4;
            if (proj < 2){
                unsigned short* base = qkb + (((((size_t)proj*Bv + b)*Hv + h)*Sv + s)*Dv + d);
                #pragma unroll
                for (int r2 = 0; r2 < 4; ++r2)
                    base[(size_t)r2*Dv] = f2b(acc[mf][nf][r2] + bvv);
            } else {
                u16x4 o = { f2b(acc[mf][nf][0]+bvv), f2b(acc[mf][nf][1]+bvv),
                            f2b(acc[mf][nf][2]+bvv), f2b(acc[mf][nf][3]+bvv) };
                *(u16x4*)(vtb + ((((size_t)b*Hv + h)*Dv + d)*Sv + s)) = o;
            }
        }
    }
}

// ---------------------------------------------------------------------------
// Fused attention v4: global_load_lds staging (zero staging VGPRs), pipelined
// issue points (K/DE after B3, V after PV), P aliases wave-local t1c,
// b-based XCD remap so each batch's K/V/lvl stays in one XCD's L2.
// ---------------------------------------------------------------------------
__global__ __launch_bounds__(256,3) void attn(
    const unsigned short* __restrict__ qkb,
    const unsigned short* __restrict__ vtb,
    const unsigned short* __restrict__ deb,    // [1023][64] bf16
    const unsigned short* __restrict__ lvlb,   // [16][512][512] bf16, prescaled
    float* __restrict__ out)
{
    __shared__ __align__(16) unsigned short sm[25216];
    unsigned short* ks  = sm;            // [64][64] swz (8KB)
    unsigned short* vsq = sm + 4096;     // [64][64] swz (8KB)
    unsigned short* des = sm + 8192;     // [128][64] swz (16KB)
    unsigned short* t1c = sm + 16384;    // [64][72] t1c[ll][rl]; P alias (9216B)
    unsigned short* t2c = sm + 20992;    // [64][66] t2c[rl][ll]  (8448B)

    const int t = threadIdx.x, w = t >> 6, lane = t & 63, g = lane >> 4, cc = lane & 15;
    const int lr8 = lane >> 3, lc8 = lane & 7;     // staging row/col within wave seg

    // b-based XCD remap: all blocks of batch b (12 h x 8 lt) on XCD b%8
    const int wg = blockIdx.x;
    const int xcd = wg & 7, inner = wg >> 3;
    const int b  = ((inner & 1) << 3) | xcd;
    const int r2 = inner >> 1;
    const int h  = r2 % 12, lt = r2 / 12;
    const int l0 = lt * 64;

    const unsigned short* qp = qkb + ((((size_t)0*Bv + b)*Hv + h)*Sv + l0)*Dv;
    const unsigned short* kp = qkb + ((((size_t)1*Bv + b)*Hv + h)*Sv)*Dv;
    const unsigned short* vp = vtb + (((size_t)b*Hv + h)*Dv)*Sv;
    const unsigned short* lvp = lvlb + ((size_t)b*Sv + l0)*Sv;

    const f32x4 fz = {0.f,0.f,0.f,0.f};
    const int llb = w*16 + g*4;

    // ---- staging helpers: LDS linear, source pre-swizzled (XOR in global col)
    auto stage_k = [&](int r0){
        #pragma unroll
        for (int j = 0; j < 2; ++j){
            int row = w*16 + j*8 + lr8;
            int ch  = lc8 ^ (row & 7);
            gload16(kp + (size_t)(r0 + row)*64 + ch*8, ks + w*1024 + j*512);
        }
    };
    auto stage_de = [&](int r0){
        const int base = l0 - r0 + 448;
        #pragma unroll
        for (int j = 0; j < 4; ++j){
            int row = w*32 + j*8 + lr8;
            int gr = base + row; if (gr > 1022) gr = 1022; if (gr < 0) gr = 0;
            int ch  = lc8 ^ (row & 7);
            gload16(deb + (size_t)gr*64 + ch*8, des + w*2048 + j*512);
        }
    };
    auto stage_v = [&](int r0){
        #pragma unroll
        for (int j = 0; j < 2; ++j){
            int row = w*16 + j*8 + lr8;
            int ch  = lc8 ^ (row & 7);
            gload16(vp + (size_t)row*512 + r0 + ch*8, vsq + w*1024 + j*512);
        }
    };

    // ---- prologue: Q frags straight from global; issue chunk-0 tiles
    bf8_t qf0, qf1;
    {
        int qrow = w*16 + cc;
        qf0 = *(const bf8_t*)(qp + (size_t)qrow*64 + g*8);
        qf1 = *(const bf8_t*)(qp + (size_t)qrow*64 + (g+4)*8);
    }
    stage_k(0); stage_de(0); stage_v(0);
    __syncthreads();                       // drains vmcnt; chunk-0 tiles ready

    float m_run[4] = {-1e30f,-1e30f,-1e30f,-1e30f};
    float l_run[4] = {0.f,0.f,0.f,0.f};
    f32x4 ctx[4] = {fz,fz,fz,fz};

    for (int c8 = 0; c8 < 8; ++c8){
        const int r0 = c8 * 64;
        // lvl gather for this chunk (consumed post-B3; MFMA phase covers latency)
        unsigned short lv[4][4];
        #pragma unroll
        for (int i = 0; i < 4; ++i){
            int rl = ((w + i) & 3)*16 + cc;
            #pragma unroll
            for (int reg = 0; reg < 4; ++reg)
                lv[reg][i] = lvp[(size_t)(llb + reg)*512 + r0 + rl];
        }

        // ---- MFMA phase ----
        __builtin_amdgcn_s_setprio(1);
        f32x4 accs[4];
        bf8_t kf0, kf1;
        #pragma unroll
        for (int i = 0; i < 4; ++i){                    // S = Q K^T (nf = (w+i)&3)
            int row = ((w + i) & 3)*16 + cc;
            bf8_t b0 = *(const bf8_t*)&ks[row*64 + ((g       ^ (row & 7))*8)];
            bf8_t b1 = *(const bf8_t*)&ks[row*64 + (((g + 4) ^ (row & 7))*8)];
            if (i == 0){ kf0 = b0; kf1 = b1; }
            f32x4 a = fz;
            a = __builtin_amdgcn_mfma_f32_16x16x32_bf16(qf0, b0, a, 0,0,0);
            a = __builtin_amdgcn_mfma_f32_16x16x32_bf16(qf1, b1, a, 0,0,0);
            accs[i] = a;
        }
        #pragma unroll
        for (int i = 0; i < 5; ++i){                    // T1 = Q DE^T, band store
            int jb = (w + i)*16 + cc;
            bf8_t d0 = *(const bf8_t*)&des[jb*64 + ((g       ^ (jb & 7))*8)];
            bf8_t d1 = *(const bf8_t*)&des[jb*64 + (((g + 4) ^ (jb & 7))*8)];
            f32x4 a = fz;
            a = __builtin_amdgcn_mfma_f32_16x16x32_bf16(qf0, d0, a, 0,0,0);
            a = __builtin_amdgcn_mfma_f32_16x16x32_bf16(qf1, d1, a, 0,0,0);
            #pragma unroll
            for (int reg = 0; reg < 4; ++reg){
                int ll = llb + reg;
                int rl = ll + 63 - jb;
                if (rl >= 0 && rl < 64) t1c[ll*72 + rl] = f2b(a[reg]);
            }
        }
        #pragma unroll
        for (int i = 0; i < 5; ++i){                    // T2 = K DE^T, band store
            int jb = (3 - w + i)*16 + cc;
            bf8_t d0 = *(const bf8_t*)&des[jb*64 + ((g       ^ (jb & 7))*8)];
            bf8_t d1 = *(const bf8_t*)&des[jb*64 + (((g + 4) ^ (jb & 7))*8)];
            f32x4 a = fz;
            a = __builtin_amdgcn_mfma_f32_16x16x32_bf16(kf0, d0, a, 0,0,0);
            a = __builtin_amdgcn_mfma_f32_16x16x32_bf16(kf1, d1, a, 0,0,0);
            #pragma unroll
            for (int reg = 0; reg < 4; ++reg){
                int rl = llb + reg;
                int ll = rl + jb - 63;
                if (ll >= 0 && ll < 64) t2c[rl*66 + ll] = f2b(a[reg]);
            }
        }
        __builtin_amdgcn_s_setprio(0);
        __syncthreads();                                // B3: t1c/t2c visible; ks/des free

        // issue next-chunk K + DE (land during epilogue+PV; drained at B1)
        if (c8 < 7){ stage_k(r0 + 64); stage_de(r0 + 64); }

        // ---- epilogue: combine + online softmax (exp2 domain) ----
        float sv[4][4];                                 // [reg][i]
        #pragma unroll
        for (int i = 0; i < 4; ++i){
            int rl = ((w + i) & 3)*16 + cc;
            #pragma unroll
            for (int reg = 0; reg < 4; ++reg){
                int ll = llb + reg;
                float t1v = b2f(t1c[ll*72 + rl]);
                float t2v = b2f(t2c[rl*66 + ll]);
                sv[reg][i] = (accs[i][reg] + t1v + t2v) * RS + b2f(lv[reg][i]);
            }
        }
        unsigned short* P = t1c;                        // alias, wave-local rows
        #pragma unroll
        for (int reg = 0; reg < 4; ++reg){
            float rmax = fmaxf(fmaxf(sv[reg][0], sv[reg][1]), fmaxf(sv[reg][2], sv[reg][3]));
            rmax = fmaxf(rmax, __shfl_xor(rmax, 1));
            rmax = fmaxf(rmax, __shfl_xor(rmax, 2));
            rmax = fmaxf(rmax, __shfl_xor(rmax, 4));
            rmax = fmaxf(rmax, __shfl_xor(rmax, 8));
            float mnew = fmaxf(m_run[reg], rmax);
            float resc = __builtin_amdgcn_exp2f(m_run[reg] - mnew);
            float ps = 0.f;
            int ll = llb + reg;
            #pragma unroll
            for (int i = 0; i < 4; ++i){
                int rl = ((w + i) & 3)*16 + cc;
                float p = __builtin_amdgcn_exp2f(sv[reg][i] - mnew);
                ps += p;
                P[ll*72 + rl] = f2b(p);
            }
            ps += __shfl_xor(ps, 1); ps += __shfl_xor(ps, 2);
            ps += __shfl_xor(ps, 4); ps += __shfl_xor(ps, 8);
            l_run[reg] = l_run[reg]*resc + ps;
            m_run[reg] = mnew;
            ctx[0][reg] *= resc; ctx[1][reg] *= resc;
            ctx[2][reg] *= resc; ctx[3][reg] *= resc;
        }

        // ---- PV (wave-local P round trip) ----
        __builtin_amdgcn_s_setprio(1);
        #pragma unroll
        for (int kh = 0; kh < 2; ++kh){
            int prow = w*16 + cc;
            bf8_t pf = *(const bf8_t*)&P[prow*72 + g*8 + kh*32];
            #pragma unroll
            for (int nf = 0; nf < 4; ++nf){
                int vr = nf*16 + cc;
                bf8_t vf = *(const bf8_t*)&vsq[vr*64 + (((g + 4*kh) ^ (vr & 7))*8)];
                ctx[nf] = __builtin_amdgcn_mfma_f32_16x16x32_bf16(pf, vf, ctx[nf], 0,0,0);
            }
        }
        __builtin_amdgcn_s_setprio(0);

        if (c8 < 7){
            __syncthreads();            // B1: PV done everywhere; drains K/DE loads
            stage_v(r0 + 64);
            __syncthreads();            // B2: drains V; all next tiles ready
        }
    }

    #pragma unroll
    for (int nf = 0; nf < 4; ++nf){
        #pragma unroll
        for (int reg = 0; reg < 4; ++reg){
            int ll = llb + reg;
            out[((size_t)b*Sv + l0 + ll)*HIDv + h*64 + nf*16 + cc] = ctx[nf][reg] / l_run[reg];
        }
    }
}

extern "C" void kernel_launch(void* const* d_in, const int* in_sizes, int n_in,
                              void* d_out, int out_size, void* d_ws, size_t ws_size,
                              hipStream_t stream)
{
    const float* hs   = (const float*)d_in[0];
    const float* mask = (const float*)d_in[1];
    const int*   cmat = (const int*)  d_in[2];
    const int*   wmat = (const int*)  d_in[3];
    const float* Wq   = (const float*)d_in[4];
    const float* bq   = (const float*)d_in[5];
    const float* Wk   = (const float*)d_in[6];
    const float* bk   = (const float*)d_in[7];
    const float* Wv   = (const float*)d_in[8];
    const float* bv   = (const float*)d_in[9];
    const float* de   = (const float*)d_in[10];
    const float* ce   = (const float*)d_in[11];
    const float* we   = (const float*)d_in[12];
    float* out = (float*)d_out;

    unsigned short* Xb   = (unsigned short*)d_ws;        // 8192*768
    unsigned short* Wb   = Xb   + 6291456;               // 2304*768
    unsigned short* deb  = Wb   + 1769472;               // 1023*64 (padded)
    unsigned short* qkb  = deb  + 65536;                 // 2*16*12*512*64
    unsigned short* vtb  = qkb  + 12582912;              // 16*12*64*512
    unsigned short* lvlb = vtb  + 6291456;               // 16*512*512

    cvt_bf16<<<2048, 256, 0, stream>>>(hs, Xb, 1572864);
    cvt_w3<<<1728, 256, 0, stream>>>(Wq, Wk, Wv, Wb, 147456);
    cvt_bf16<<<64,   256, 0, stream>>>(de, deb, 16368);
    prep_bias<<<8192, 256, 0, stream>>>(cmat, wmat, mask, ce, we, lvlb);

    qkv_gemm<<<dim3(64, 18), 256, 0, stream>>>(Xb, Wb, bq, bk, bv, qkb, vtb);
    attn<<<1536, 256, 0, stream>>>(qkb, vtb, deb, lvlb, out);
}

// Round 5
// 177.408 us; speedup vs baseline: 2.4731x; 1.7024x over previous
//
#include <hip/hip_runtime.h>
#include <stdint.h>

#define Bv 16
#define Sv 512
#define Hv 12
#define Dv 64
#define HIDv 768

typedef __attribute__((ext_vector_type(8))) short bf8_t;
typedef __attribute__((ext_vector_type(4))) float f32x4;
typedef __attribute__((ext_vector_type(8))) unsigned short u16x8;
typedef __attribute__((ext_vector_type(4))) unsigned short u16x4;

__device__ __forceinline__ float b2f(unsigned short u){
    union { unsigned int i; float f; } x; x.i = ((unsigned int)u) << 16; return x.f;
}
__device__ __forceinline__ unsigned short f2b(float f){
    union { float f; unsigned int i; } x; x.f = f;
    unsigned int r = x.i + 0x7fff + ((x.i >> 16) & 1);
    return (unsigned short)(r >> 16);
}
__device__ __forceinline__ void gload16(const unsigned short* g, unsigned short* l){
    __builtin_amdgcn_global_load_lds(
        (const __attribute__((address_space(1))) void*)g,
        (__attribute__((address_space(3))) void*)l, 16, 0, 0);
}

#define RS 0.18033688f          /* 0.125 * log2(e) */
#define LOG2E 1.44269504f

// ---------------------------------------------------------------------------
__global__ void cvt_bf16(const float* __restrict__ src, unsigned short* __restrict__ dst, int n4){
    int i = blockIdx.x * 256 + threadIdx.x;
    int stride = gridDim.x * 256;
    for (; i < n4; i += stride){
        float4 v = ((const float4*)src)[i];
        u16x4 o = { f2b(v.x), f2b(v.y), f2b(v.z), f2b(v.w) };
        ((u16x4*)dst)[i] = o;
    }
}

__global__ void cvt_w3(const float* __restrict__ a, const float* __restrict__ b,
                       const float* __restrict__ c, unsigned short* __restrict__ dst, int n4each){
    int i = blockIdx.x * 256 + threadIdx.x;
    if (i >= 3*n4each) return;
    int which = i / n4each, j = i - which*n4each;
    const float* src = which == 0 ? a : (which == 1 ? b : c);
    float4 v = ((const float4*)src)[j];
    u16x4 o = { f2b(v.x), f2b(v.y), f2b(v.z), f2b(v.w) };
    ((u16x4*)dst)[i] = o;
}

// ---------------------------------------------------------------------------
// lvl[b][l][r] = (0.5*ce[c]+0.5*we[w])*RS + mask[b][r]*LOG2E   (bf16)
// ---------------------------------------------------------------------------
__global__ __launch_bounds__(256) void prep_bias(
    const int* __restrict__ cmat, const int* __restrict__ wmat,
    const float* __restrict__ mask, const float* __restrict__ ce, const float* __restrict__ we,
    unsigned short* __restrict__ lvlb)
{
    __shared__ float tab[64];
    const int t = threadIdx.x;
    if (t < 64) tab[t] = (0.5f*ce[t>>3] + 0.5f*we[t&7]) * RS;
    __syncthreads();
    const size_t row = blockIdx.x;            // b*512 + l
    const int b = (int)(row >> 9);
    const size_t base = row * 512;
    int2 c2 = *(const int2*)(cmat + base + t*2);
    int2 w2 = *(const int2*)(wmat + base + t*2);
    float2 m2 = *(const float2*)(mask + (size_t)b*512 + t*2);
    unsigned short o0 = f2b(tab[(c2.x<<3)|w2.x] + m2.x * LOG2E);
    unsigned short o1 = f2b(tab[(c2.y<<3)|w2.y] + m2.y * LOG2E);
    *(unsigned int*)(lvlb + base + t*2) = (unsigned)o0 | ((unsigned)o1 << 16);
}

// ---------------------------------------------------------------------------
// QKV projection (verified): Q,K -> [proj][b][h][s][d], V -> [b][h][d][s]
// ---------------------------------------------------------------------------
__global__ __launch_bounds__(256,3) void qkv_gemm(
    const unsigned short* __restrict__ Xb,
    const unsigned short* __restrict__ Wb,
    const float* __restrict__ bq, const float* __restrict__ bk, const float* __restrict__ bv,
    unsigned short* __restrict__ qkb,
    unsigned short* __restrict__ vtb)
{
    __shared__ unsigned short Ab[128*40];
    __shared__ unsigned short Bb[128*40];
    const int t = threadIdx.x;
    const int w = t >> 6, lane = t & 63, g = lane >> 4, cc = lane & 15;
    const int wm = w >> 1, wn = w & 1;
    const int m0 = blockIdx.x * 128;
    const int n0 = blockIdx.y * 128;

    const f32x4 fz = {0.f,0.f,0.f,0.f};
    f32x4 acc[4][4];
    #pragma unroll
    for (int i = 0; i < 4; ++i)
        #pragma unroll
        for (int j = 0; j < 4; ++j) acc[i][j] = fz;

    u16x8 pa[2], pb[2];
    #pragma unroll
    for (int r = 0; r < 2; ++r){
        int chunk = t + r*256; int row = chunk >> 2; int ch = chunk & 3;
        pa[r] = *(const u16x8*)(Xb + (size_t)(m0+row)*768 + ch*8);
        pb[r] = *(const u16x8*)(Wb + (size_t)(n0+row)*768 + ch*8);
    }
    for (int k0 = 0; k0 < 768; k0 += 32){
        __syncthreads();
        #pragma unroll
        for (int r = 0; r < 2; ++r){
            int chunk = t + r*256; int row = chunk >> 2; int ch = chunk & 3;
            *(u16x8*)&Ab[row*40 + ch*8] = pa[r];
            *(u16x8*)&Bb[row*40 + ch*8] = pb[r];
        }
        __syncthreads();
        if (k0 + 32 < 768){
            #pragma unroll
            for (int r = 0; r < 2; ++r){
                int chunk = t + r*256; int row = chunk >> 2; int ch = chunk & 3;
                pa[r] = *(const u16x8*)(Xb + (size_t)(m0+row)*768 + (k0+32) + ch*8);
                pb[r] = *(const u16x8*)(Wb + (size_t)(n0+row)*768 + (k0+32) + ch*8);
            }
        }
        bf8_t af[4], bfr[4];
        #pragma unroll
        for (int mf = 0; mf < 4; ++mf)
            af[mf] = *(const bf8_t*)&Ab[(wm*64 + mf*16 + cc)*40 + g*8];
        #pragma unroll
        for (int nf = 0; nf < 4; ++nf)
            bfr[nf] = *(const bf8_t*)&Bb[(wn*64 + nf*16 + cc)*40 + g*8];
        #pragma unroll
        for (int mf = 0; mf < 4; ++mf)
            #pragma unroll
            for (int nf = 0; nf < 4; ++nf)
                acc[mf][nf] = __builtin_amdgcn_mfma_f32_16x16x32_bf16(af[mf], bfr[nf], acc[mf][nf], 0,0,0);
    }

    const int b  = m0 >> 9;
    const int s0 = (m0 & 511) + wm*64;
    const int nbase = n0 + wn*64;
    const int proj = nbase / 768;
    const int nin0 = nbase % 768;
    const float* bias = proj == 0 ? bq : (proj == 1 ? bk : bv);
    #pragma unroll
    for (int nf = 0; nf < 4; ++nf){
        int nin = nin0 + nf*16 + cc;
        int h = nin >> 6, d = nin & 63;
        float bvv = bias[nin];
        #pragma unroll
        for (int mf = 0; mf < 4; ++mf){
            int s = s0 + mf*16 + g*4;
            if (proj < 2){
                unsigned short* base = qkb + (((((size_t)proj*Bv + b)*Hv + h)*Sv + s)*Dv + d);
                #pragma unroll
                for (int r2 = 0; r2 < 4; ++r2)
                    base[(size_t)r2*Dv] = f2b(acc[mf][nf][r2] + bvv);
            } else {
                u16x4 o = { f2b(acc[mf][nf][0]+bvv), f2b(acc[mf][nf][1]+bvv),
                            f2b(acc[mf][nf][2]+bvv), f2b(acc[mf][nf][3]+bvv) };
                *(u16x4*)(vtb + ((((size_t)b*Hv + h)*Dv + d)*Sv + s)) = o;
            }
        }
    }
}

// ---------------------------------------------------------------------------
// Fused attention v5: identical to v4 except __launch_bounds__(256,2) --
// the (256,3) bound capped the unified VGPR/AGPR budget and forced a
// per-chunk scratch spill (R3: 502MB, R4: 89MB WRITE_SIZE). LDS is 50.4KB
// so occupancy should stay 3 blocks/CU via the LDS limit.
// ---------------------------------------------------------------------------
__global__ __launch_bounds__(256,2) void attn(
    const unsigned short* __restrict__ qkb,
    const unsigned short* __restrict__ vtb,
    const unsigned short* __restrict__ deb,    // [1023][64] bf16
    const unsigned short* __restrict__ lvlb,   // [16][512][512] bf16, prescaled
    float* __restrict__ out)
{
    __shared__ __align__(16) unsigned short sm[25216];
    unsigned short* ks  = sm;            // [64][64] swz (8KB)
    unsigned short* vsq = sm + 4096;     // [64][64] swz (8KB)
    unsigned short* des = sm + 8192;     // [128][64] swz (16KB)
    unsigned short* t1c = sm + 16384;    // [64][72] t1c[ll][rl]; P alias (9216B)
    unsigned short* t2c = sm + 20992;    // [64][66] t2c[rl][ll]  (8448B)

    const int t = threadIdx.x, w = t >> 6, lane = t & 63, g = lane >> 4, cc = lane & 15;
    const int lr8 = lane >> 3, lc8 = lane & 7;     // staging row/col within wave seg

    // b-based XCD remap: all blocks of batch b (12 h x 8 lt) on XCD b%8
    const int wg = blockIdx.x;
    const int xcd = wg & 7, inner = wg >> 3;
    const int b  = ((inner & 1) << 3) | xcd;
    const int r2 = inner >> 1;
    const int h  = r2 % 12, lt = r2 / 12;
    const int l0 = lt * 64;

    const unsigned short* qp = qkb + ((((size_t)0*Bv + b)*Hv + h)*Sv + l0)*Dv;
    const unsigned short* kp = qkb + ((((size_t)1*Bv + b)*Hv + h)*Sv)*Dv;
    const unsigned short* vp = vtb + (((size_t)b*Hv + h)*Dv)*Sv;
    const unsigned short* lvp = lvlb + ((size_t)b*Sv + l0)*Sv;

    const f32x4 fz = {0.f,0.f,0.f,0.f};
    const int llb = w*16 + g*4;

    // ---- staging helpers: LDS linear, source pre-swizzled (XOR in global col)
    auto stage_k = [&](int r0){
        #pragma unroll
        for (int j = 0; j < 2; ++j){
            int row = w*16 + j*8 + lr8;
            int ch  = lc8 ^ (row & 7);
            gload16(kp + (size_t)(r0 + row)*64 + ch*8, ks + w*1024 + j*512);
        }
    };
    auto stage_de = [&](int r0){
        const int base = l0 - r0 + 448;
        #pragma unroll
        for (int j = 0; j < 4; ++j){
            int row = w*32 + j*8 + lr8;
            int gr = base + row; if (gr > 1022) gr = 1022; if (gr < 0) gr = 0;
            int ch  = lc8 ^ (row & 7);
            gload16(deb + (size_t)gr*64 + ch*8, des + w*2048 + j*512);
        }
    };
    auto stage_v = [&](int r0){
        #pragma unroll
        for (int j = 0; j < 2; ++j){
            int row = w*16 + j*8 + lr8;
            int ch  = lc8 ^ (row & 7);
            gload16(vp + (size_t)row*512 + r0 + ch*8, vsq + w*1024 + j*512);
        }
    };

    // ---- prologue: Q frags straight from global; issue chunk-0 tiles
    bf8_t qf0, qf1;
    {
        int qrow = w*16 + cc;
        qf0 = *(const bf8_t*)(qp + (size_t)qrow*64 + g*8);
        qf1 = *(const bf8_t*)(qp + (size_t)qrow*64 + (g+4)*8);
    }
    stage_k(0); stage_de(0); stage_v(0);
    __syncthreads();                       // drains vmcnt; chunk-0 tiles ready

    float m_run[4] = {-1e30f,-1e30f,-1e30f,-1e30f};
    float l_run[4] = {0.f,0.f,0.f,0.f};
    f32x4 ctx[4] = {fz,fz,fz,fz};

    for (int c8 = 0; c8 < 8; ++c8){
        const int r0 = c8 * 64;
        // lvl gather for this chunk (consumed post-B3; MFMA phase covers latency)
        unsigned short lv[4][4];
        #pragma unroll
        for (int i = 0; i < 4; ++i){
            int rl = ((w + i) & 3)*16 + cc;
            #pragma unroll
            for (int reg = 0; reg < 4; ++reg)
                lv[reg][i] = lvp[(size_t)(llb + reg)*512 + r0 + rl];
        }

        // ---- MFMA phase ----
        __builtin_amdgcn_s_setprio(1);
        f32x4 accs[4];
        bf8_t kf0, kf1;
        #pragma unroll
        for (int i = 0; i < 4; ++i){                    // S = Q K^T (nf = (w+i)&3)
            int row = ((w + i) & 3)*16 + cc;
            bf8_t b0 = *(const bf8_t*)&ks[row*64 + ((g       ^ (row & 7))*8)];
            bf8_t b1 = *(const bf8_t*)&ks[row*64 + (((g + 4) ^ (row & 7))*8)];
            if (i == 0){ kf0 = b0; kf1 = b1; }
            f32x4 a = fz;
            a = __builtin_amdgcn_mfma_f32_16x16x32_bf16(qf0, b0, a, 0,0,0);
            a = __builtin_amdgcn_mfma_f32_16x16x32_bf16(qf1, b1, a, 0,0,0);
            accs[i] = a;
        }
        #pragma unroll
        for (int i = 0; i < 5; ++i){                    // T1 = Q DE^T, band store
            int jb = (w + i)*16 + cc;
            bf8_t d0 = *(const bf8_t*)&des[jb*64 + ((g       ^ (jb & 7))*8)];
            bf8_t d1 = *(const bf8_t*)&des[jb*64 + (((g + 4) ^ (jb & 7))*8)];
            f32x4 a = fz;
            a = __builtin_amdgcn_mfma_f32_16x16x32_bf16(qf0, d0, a, 0,0,0);
            a = __builtin_amdgcn_mfma_f32_16x16x32_bf16(qf1, d1, a, 0,0,0);
            #pragma unroll
            for (int reg = 0; reg < 4; ++reg){
                int ll = llb + reg;
                int rl = ll + 63 - jb;
                if (rl >= 0 && rl < 64) t1c[ll*72 + rl] = f2b(a[reg]);
            }
        }
        #pragma unroll
        for (int i = 0; i < 5; ++i){                    // T2 = K DE^T, band store
            int jb = (3 - w + i)*16 + cc;
            bf8_t d0 = *(const bf8_t*)&des[jb*64 + ((g       ^ (jb & 7))*8)];
            bf8_t d1 = *(const bf8_t*)&des[jb*64 + (((g + 4) ^ (jb & 7))*8)];
            f32x4 a = fz;
            a = __builtin_amdgcn_mfma_f32_16x16x32_bf16(kf0, d0, a, 0,0,0);
            a = __builtin_amdgcn_mfma_f32_16x16x32_bf16(kf1, d1, a, 0,0,0);
            #pragma unroll
            for (int reg = 0; reg < 4; ++reg){
                int rl = llb + reg;
                int ll = rl + jb - 63;
                if (ll >= 0 && ll < 64) t2c[rl*66 + ll] = f2b(a[reg]);
            }
        }
        __builtin_amdgcn_s_setprio(0);
        __syncthreads();                                // B3: t1c/t2c visible; ks/des free

        // issue next-chunk K + DE (land during epilogue+PV; drained at B1)
        if (c8 < 7){ stage_k(r0 + 64); stage_de(r0 + 64); }

        // ---- epilogue: combine + online softmax (exp2 domain) ----
        float sv[4][4];                                 // [reg][i]
        #pragma unroll
        for (int i = 0; i < 4; ++i){
            int rl = ((w + i) & 3)*16 + cc;
            #pragma unroll
            for (int reg = 0; reg < 4; ++reg){
                int ll = llb + reg;
                float t1v = b2f(t1c[ll*72 + rl]);
                float t2v = b2f(t2c[rl*66 + ll]);
                sv[reg][i] = (accs[i][reg] + t1v + t2v) * RS + b2f(lv[reg][i]);
            }
        }
        unsigned short* P = t1c;                        // alias, wave-local rows
        #pragma unroll
        for (int reg = 0; reg < 4; ++reg){
            float rmax = fmaxf(fmaxf(sv[reg][0], sv[reg][1]), fmaxf(sv[reg][2], sv[reg][3]));
            rmax = fmaxf(rmax, __shfl_xor(rmax, 1));
            rmax = fmaxf(rmax, __shfl_xor(rmax, 2));
            rmax = fmaxf(rmax, __shfl_xor(rmax, 4));
            rmax = fmaxf(rmax, __shfl_xor(rmax, 8));
            float mnew = fmaxf(m_run[reg], rmax);
            float resc = __builtin_amdgcn_exp2f(m_run[reg] - mnew);
            float ps = 0.f;
            int ll = llb + reg;
            #pragma unroll
            for (int i = 0; i < 4; ++i){
                int rl = ((w + i) & 3)*16 + cc;
                float p = __builtin_amdgcn_exp2f(sv[reg][i] - mnew);
                ps += p;
                P[ll*72 + rl] = f2b(p);
            }
            ps += __shfl_xor(ps, 1); ps += __shfl_xor(ps, 2);
            ps += __shfl_xor(ps, 4); ps += __shfl_xor(ps, 8);
            l_run[reg] = l_run[reg]*resc + ps;
            m_run[reg] = mnew;
            ctx[0][reg] *= resc; ctx[1][reg] *= resc;
            ctx[2][reg] *= resc; ctx[3][reg] *= resc;
        }

        // ---- PV (wave-local P round trip) ----
        __builtin_amdgcn_s_setprio(1);
        #pragma unroll
        for (int kh = 0; kh < 2; ++kh){
            int prow = w*16 + cc;
            bf8_t pf = *(const bf8_t*)&P[prow*72 + g*8 + kh*32];
            #pragma unroll
            for (int nf = 0; nf < 4; ++nf){
                int vr = nf*16 + cc;
                bf8_t vf = *(const bf8_t*)&vsq[vr*64 + (((g + 4*kh) ^ (vr & 7))*8)];
                ctx[nf] = __builtin_amdgcn_mfma_f32_16x16x32_bf16(pf, vf, ctx[nf], 0,0,0);
            }
        }
        __builtin_amdgcn_s_setprio(0);

        if (c8 < 7){
            __syncthreads();            // B1: PV done everywhere; drains K/DE loads
            stage_v(r0 + 64);
            __syncthreads();            // B2: drains V; all next tiles ready
        }
    }

    #pragma unroll
    for (int nf = 0; nf < 4; ++nf){
        #pragma unroll
        for (int reg = 0; reg < 4; ++reg){
            int ll = llb + reg;
            out[((size_t)b*Sv + l0 + ll)*HIDv + h*64 + nf*16 + cc] = ctx[nf][reg] / l_run[reg];
        }
    }
}

extern "C" void kernel_launch(void* const* d_in, const int* in_sizes, int n_in,
                              void* d_out, int out_size, void* d_ws, size_t ws_size,
                              hipStream_t stream)
{
    const float* hs   = (const float*)d_in[0];
    const float* mask = (const float*)d_in[1];
    const int*   cmat = (const int*)  d_in[2];
    const int*   wmat = (const int*)  d_in[3];
    const float* Wq   = (const float*)d_in[4];
    const float* bq   = (const float*)d_in[5];
    const float* Wk   = (const float*)d_in[6];
    const float* bk   = (const float*)d_in[7];
    const float* Wv   = (const float*)d_in[8];
    const float* bv   = (const float*)d_in[9];
    const float* de   = (const float*)d_in[10];
    const float* ce   = (const float*)d_in[11];
    const float* we   = (const float*)d_in[12];
    float* out = (float*)d_out;

    unsigned short* Xb   = (unsigned short*)d_ws;        // 8192*768
    unsigned short* Wb   = Xb   + 6291456;               // 2304*768
    unsigned short* deb  = Wb   + 1769472;               // 1023*64 (padded)
    unsigned short* qkb  = deb  + 65536;                 // 2*16*12*512*64
    unsigned short* vtb  = qkb  + 12582912;              // 16*12*64*512
    unsigned short* lvlb = vtb  + 6291456;               // 16*512*512

    cvt_bf16<<<2048, 256, 0, stream>>>(hs, Xb, 1572864);
    cvt_w3<<<1728, 256, 0, stream>>>(Wq, Wk, Wv, Wb, 147456);
    cvt_bf16<<<64,   256, 0, stream>>>(de, deb, 16368);
    prep_bias<<<8192, 256, 0, stream>>>(cmat, wmat, mask, ce, we, lvlb);

    qkv_gemm<<<dim3(64, 18), 256, 0, stream>>>(Xb, Wb, bq, bk, bv, qkb, vtb);
    attn<<<1536, 256, 0, stream>>>(qkb, vtb, deb, lvlb, out);
}

// Round 6
// 157.327 us; speedup vs baseline: 2.7888x; 1.1276x over previous
//
#include <hip/hip_runtime.h>
#include <stdint.h>

#define Bv 16
#define Sv 512
#define Hv 12
#define Dv 64
#define HIDv 768

typedef __attribute__((ext_vector_type(8))) short bf8_t;
typedef __attribute__((ext_vector_type(4))) float f32x4;
typedef __attribute__((ext_vector_type(8))) unsigned short u16x8;
typedef __attribute__((ext_vector_type(4))) unsigned short u16x4;

__device__ __forceinline__ float b2f(unsigned short u){
    union { unsigned int i; float f; } x; x.i = ((unsigned int)u) << 16; return x.f;
}
__device__ __forceinline__ unsigned short f2b(float f){
    union { float f; unsigned int i; } x; x.f = f;
    unsigned int r = x.i + 0x7fff + ((x.i >> 16) & 1);
    return (unsigned short)(r >> 16);
}
__device__ __forceinline__ void gload16(const unsigned short* g, unsigned short* l){
    __builtin_amdgcn_global_load_lds(
        (const __attribute__((address_space(1))) void*)g,
        (__attribute__((address_space(3))) void*)l, 16, 0, 0);
}

#define RS 0.18033688f          /* 0.125 * log2(e) */
#define LOG2E 1.44269504f

// ---------------------------------------------------------------------------
__global__ void cvt_bf16(const float* __restrict__ src, unsigned short* __restrict__ dst, int n4){
    int i = blockIdx.x * 256 + threadIdx.x;
    int stride = gridDim.x * 256;
    for (; i < n4; i += stride){
        float4 v = ((const float4*)src)[i];
        u16x4 o = { f2b(v.x), f2b(v.y), f2b(v.z), f2b(v.w) };
        ((u16x4*)dst)[i] = o;
    }
}

__global__ void cvt_w3(const float* __restrict__ a, const float* __restrict__ b,
                       const float* __restrict__ c, unsigned short* __restrict__ dst, int n4each){
    int i = blockIdx.x * 256 + threadIdx.x;
    if (i >= 3*n4each) return;
    int which = i / n4each, j = i - which*n4each;
    const float* src = which == 0 ? a : (which == 1 ? b : c);
    float4 v = ((const float4*)src)[j];
    u16x4 o = { f2b(v.x), f2b(v.y), f2b(v.z), f2b(v.w) };
    ((u16x4*)dst)[i] = o;
}

// ---------------------------------------------------------------------------
// lvl bias pre-tiled to the attn fragment layout.
// block = (b*8 + lt)*8 + c8; thread t -> (w,g,cc); element (reg,i) at
// ll = lt*64+w*16+g*4+reg, rl = c8*64+i*16+cc.
// value = (0.5*ce+0.5*we)*RS + mask*LOG2E   (bf16)
// ---------------------------------------------------------------------------
__global__ __launch_bounds__(256) void prep_bias_t(
    const int* __restrict__ cmat, const int* __restrict__ wmat,
    const float* __restrict__ mask, const float* __restrict__ ce, const float* __restrict__ we,
    unsigned short* __restrict__ lvlt)
{
    __shared__ float tab[64];
    __shared__ float mrow[64];
    const int t = threadIdx.x;
    const int blk = blockIdx.x;
    const int c8 = blk & 7, lt = (blk >> 3) & 7, b = blk >> 6;
    if (t < 64) tab[t] = (0.5f*ce[t>>3] + 0.5f*we[t&7]) * RS;
    if (t >= 64 && t < 128) mrow[t-64] = mask[b*512 + c8*64 + (t-64)] * LOG2E;
    __syncthreads();
    const int w = t >> 6, lane = t & 63, g = lane >> 4, cc = lane & 15;
    const int llb = lt*64 + w*16 + g*4;
    const int rlb = c8*64 + cc;
    unsigned short o[16];
    #pragma unroll
    for (int reg = 0; reg < 4; ++reg){
        const int* cr = cmat + ((size_t)b*512 + llb + reg)*512 + rlb;
        const int* wr = wmat + ((size_t)b*512 + llb + reg)*512 + rlb;
        #pragma unroll
        for (int i = 0; i < 4; ++i){
            int cv = cr[i*16], wv = wr[i*16];
            o[reg*4 + i] = f2b(tab[(cv<<3)|wv] + mrow[i*16 + cc]);
        }
    }
    unsigned short* dst = lvlt + ((size_t)blk*256 + t)*16;
    *(u16x8*)dst       = *(u16x8*)&o[0];
    *(u16x8*)(dst + 8) = *(u16x8*)&o[8];
}

// ---------------------------------------------------------------------------
// QKV projection (verified): Q,K -> [proj][b][h][s][d], V -> [b][h][d][s]
// ---------------------------------------------------------------------------
__global__ __launch_bounds__(256,3) void qkv_gemm(
    const unsigned short* __restrict__ Xb,
    const unsigned short* __restrict__ Wb,
    const float* __restrict__ bq, const float* __restrict__ bk, const float* __restrict__ bv,
    unsigned short* __restrict__ qkb,
    unsigned short* __restrict__ vtb)
{
    __shared__ unsigned short Ab[128*40];
    __shared__ unsigned short Bb[128*40];
    const int t = threadIdx.x;
    const int w = t >> 6, lane = t & 63, g = lane >> 4, cc = lane & 15;
    const int wm = w >> 1, wn = w & 1;
    const int m0 = blockIdx.x * 128;
    const int n0 = blockIdx.y * 128;

    const f32x4 fz = {0.f,0.f,0.f,0.f};
    f32x4 acc[4][4];
    #pragma unroll
    for (int i = 0; i < 4; ++i)
        #pragma unroll
        for (int j = 0; j < 4; ++j) acc[i][j] = fz;

    u16x8 pa[2], pb[2];
    #pragma unroll
    for (int r = 0; r < 2; ++r){
        int chunk = t + r*256; int row = chunk >> 2; int ch = chunk & 3;
        pa[r] = *(const u16x8*)(Xb + (size_t)(m0+row)*768 + ch*8);
        pb[r] = *(const u16x8*)(Wb + (size_t)(n0+row)*768 + ch*8);
    }
    for (int k0 = 0; k0 < 768; k0 += 32){
        __syncthreads();
        #pragma unroll
        for (int r = 0; r < 2; ++r){
            int chunk = t + r*256; int row = chunk >> 2; int ch = chunk & 3;
            *(u16x8*)&Ab[row*40 + ch*8] = pa[r];
            *(u16x8*)&Bb[row*40 + ch*8] = pb[r];
        }
        __syncthreads();
        if (k0 + 32 < 768){
            #pragma unroll
            for (int r = 0; r < 2; ++r){
                int chunk = t + r*256; int row = chunk >> 2; int ch = chunk & 3;
                pa[r] = *(const u16x8*)(Xb + (size_t)(m0+row)*768 + (k0+32) + ch*8);
                pb[r] = *(const u16x8*)(Wb + (size_t)(n0+row)*768 + (k0+32) + ch*8);
            }
        }
        bf8_t af[4], bfr[4];
        #pragma unroll
        for (int mf = 0; mf < 4; ++mf)
            af[mf] = *(const bf8_t*)&Ab[(wm*64 + mf*16 + cc)*40 + g*8];
        #pragma unroll
        for (int nf = 0; nf < 4; ++nf)
            bfr[nf] = *(const bf8_t*)&Bb[(wn*64 + nf*16 + cc)*40 + g*8];
        #pragma unroll
        for (int mf = 0; mf < 4; ++mf)
            #pragma unroll
            for (int nf = 0; nf < 4; ++nf)
                acc[mf][nf] = __builtin_amdgcn_mfma_f32_16x16x32_bf16(af[mf], bfr[nf], acc[mf][nf], 0,0,0);
    }

    const int b  = m0 >> 9;
    const int s0 = (m0 & 511) + wm*64;
    const int nbase = n0 + wn*64;
    const int proj = nbase / 768;
    const int nin0 = nbase % 768;
    const float* bias = proj == 0 ? bq : (proj == 1 ? bk : bv);
    #pragma unroll
    for (int nf = 0; nf < 4; ++nf){
        int nin = nin0 + nf*16 + cc;
        int h = nin >> 6, d = nin & 63;
        float bvv = bias[nin];
        #pragma unroll
        for (int mf = 0; mf < 4; ++mf){
            int s = s0 + mf*16 + g*4;
            if (proj < 2){
                unsigned short* base = qkb + (((((size_t)proj*Bv + b)*Hv + h)*Sv + s)*Dv + d);
                #pragma unroll
                for (int r2 = 0; r2 < 4; ++r2)
                    base[(size_t)r2*Dv] = f2b(acc[mf][nf][r2] + bvv);
            } else {
                u16x4 o = { f2b(acc[mf][nf][0]+bvv), f2b(acc[mf][nf][1]+bvv),
                            f2b(acc[mf][nf][2]+bvv), f2b(acc[mf][nf][3]+bvv) };
                *(u16x4*)(vtb + ((((size_t)b*Hv + h)*Dv + d)*Sv + s)) = o;
            }
        }
    }
}

// ---------------------------------------------------------------------------
// Fused attention v6: f32 t1c/t2c (no cvt in band round-trip, read2-friendly),
// no max-tracking (scores bounded; softmax shift-invariant), fragment-tiled
// lvl (2 b128 loads), XOR-swizzled P (kills PV 8-way conflict).
// LDS 73.25KB -> 2 blocks/CU.
// ---------------------------------------------------------------------------
__global__ __launch_bounds__(256,2) void attn(
    const unsigned short* __restrict__ qkb,
    const unsigned short* __restrict__ vtb,
    const unsigned short* __restrict__ deb,    // [1023][64] bf16
    const unsigned short* __restrict__ lvlt,   // fragment-tiled lvl bias
    float* __restrict__ out)
{
    __shared__ __align__(16) unsigned short sm[37504];
    unsigned short* ks   = sm;                       // [64][64] swz   8192 B
    unsigned short* vsq  = sm + 4096;                // [64][64] swz   8192 B
    unsigned short* des  = sm + 8192;                // [128][64] swz 16384 B
    float*          t1c  = (float*)(sm + 16384);     // [64][66] f32  16896 B
    float*          t2c  = (float*)(sm + 24832);     // [64][67] f32  17152 B
    unsigned short* P    = sm + 33408;               // [64][64] swz   8192 B

    const int t = threadIdx.x, w = t >> 6, lane = t & 63, g = lane >> 4, cc = lane & 15;
    const int lr8 = lane >> 3, lc8 = lane & 7;

    // b-based XCD remap: all blocks of batch b on XCD b%8
    const int wg = blockIdx.x;
    const int xcd = wg & 7, inner = wg >> 3;
    const int b  = ((inner & 1) << 3) | xcd;
    const int r2 = inner >> 1;
    const int h  = r2 % 12, lt = r2 / 12;
    const int l0 = lt * 64;

    const unsigned short* qp = qkb + ((((size_t)0*Bv + b)*Hv + h)*Sv + l0)*Dv;
    const unsigned short* kp = qkb + ((((size_t)1*Bv + b)*Hv + h)*Sv)*Dv;
    const unsigned short* vp = vtb + (((size_t)b*Hv + h)*Dv)*Sv;
    const unsigned short* lvbase = lvlt + (((size_t)b*8 + lt)*8)*256*16 + (size_t)t*16;

    const f32x4 fz = {0.f,0.f,0.f,0.f};
    const int llb = w*16 + g*4;

    auto stage_k = [&](int r0){
        #pragma unroll
        for (int j = 0; j < 2; ++j){
            int row = w*16 + j*8 + lr8;
            int ch  = lc8 ^ (row & 7);
            gload16(kp + (size_t)(r0 + row)*64 + ch*8, ks + w*1024 + j*512);
        }
    };
    auto stage_de = [&](int r0){
        const int base = l0 - r0 + 448;
        #pragma unroll
        for (int j = 0; j < 4; ++j){
            int row = w*32 + j*8 + lr8;
            int gr = base + row; if (gr > 1022) gr = 1022; if (gr < 0) gr = 0;
            int ch  = lc8 ^ (row & 7);
            gload16(deb + (size_t)gr*64 + ch*8, des + w*2048 + j*512);
        }
    };
    auto stage_v = [&](int r0){
        #pragma unroll
        for (int j = 0; j < 2; ++j){
            int row = w*16 + j*8 + lr8;
            int ch  = lc8 ^ (row & 7);
            gload16(vp + (size_t)row*512 + r0 + ch*8, vsq + w*1024 + j*512);
        }
    };

    // ---- prologue: Q frags straight from global; stage chunk-0 tiles
    bf8_t qf0, qf1;
    {
        int qrow = w*16 + cc;
        qf0 = *(const bf8_t*)(qp + (size_t)qrow*64 + g*8);
        qf1 = *(const bf8_t*)(qp + (size_t)qrow*64 + (g+4)*8);
    }
    stage_k(0); stage_de(0); stage_v(0);
    __syncthreads();

    float l_run[4] = {0.f,0.f,0.f,0.f};
    f32x4 ctx[4] = {fz,fz,fz,fz};

    for (int c8 = 0; c8 < 8; ++c8){
        const int r0 = c8 * 64;
        // lvl fragment tile (global, latency hidden under MFMA phase)
        u16x8 lva = *(const u16x8*)(lvbase + (size_t)c8*256*16);
        u16x8 lvb = *(const u16x8*)(lvbase + (size_t)c8*256*16 + 8);

        // ---- MFMA phase ----
        __builtin_amdgcn_s_setprio(1);
        f32x4 accs[4];
        bf8_t kf0, kf1;
        #pragma unroll
        for (int i = 0; i < 4; ++i){                    // S = Q K^T
            int row = i*16 + cc;
            bf8_t b0 = *(const bf8_t*)&ks[row*64 + ((g       ^ (row & 7))*8)];
            bf8_t b1 = *(const bf8_t*)&ks[row*64 + (((g + 4) ^ (row & 7))*8)];
            if (i == w){ kf0 = b0; kf1 = b1; }
            f32x4 a = fz;
            a = __builtin_amdgcn_mfma_f32_16x16x32_bf16(qf0, b0, a, 0,0,0);
            a = __builtin_amdgcn_mfma_f32_16x16x32_bf16(qf1, b1, a, 0,0,0);
            accs[i] = a;
        }
        #pragma unroll
        for (int i = 0; i < 5; ++i){                    // T1 = Q DE^T, band scatter (f32)
            int jb = (w + i)*16 + cc;
            bf8_t d0 = *(const bf8_t*)&des[jb*64 + ((g       ^ (jb & 7))*8)];
            bf8_t d1 = *(const bf8_t*)&des[jb*64 + (((g + 4) ^ (jb & 7))*8)];
            f32x4 a = fz;
            a = __builtin_amdgcn_mfma_f32_16x16x32_bf16(qf0, d0, a, 0,0,0);
            a = __builtin_amdgcn_mfma_f32_16x16x32_bf16(qf1, d1, a, 0,0,0);
            #pragma unroll
            for (int reg = 0; reg < 4; ++reg){
                int ll = llb + reg;
                int rl = ll + 63 - jb;
                if (rl >= 0 && rl < 64) t1c[ll*66 + rl] = a[reg];
            }
        }
        #pragma unroll
        for (int i = 0; i < 5; ++i){                    // T2 = K DE^T, band scatter (f32)
            int jb = (3 - w + i)*16 + cc;
            bf8_t d0 = *(const bf8_t*)&des[jb*64 + ((g       ^ (jb & 7))*8)];
            bf8_t d1 = *(const bf8_t*)&des[jb*64 + (((g + 4) ^ (jb & 7))*8)];
            f32x4 a = fz;
            a = __builtin_amdgcn_mfma_f32_16x16x32_bf16(kf0, d0, a, 0,0,0);
            a = __builtin_amdgcn_mfma_f32_16x16x32_bf16(kf1, d1, a, 0,0,0);
            #pragma unroll
            for (int reg = 0; reg < 4; ++reg){
                int rl = llb + reg;
                int ll = rl + jb - 63;
                if (ll >= 0 && ll < 64) t2c[rl*67 + ll] = a[reg];
            }
        }
        __builtin_amdgcn_s_setprio(0);
        __syncthreads();                                // B3: t1c/t2c visible; ks/des free

        if (c8 < 7){ stage_k(r0 + 64); stage_de(r0 + 64); }

        // ---- epilogue: gather (f32), combine, exp2, P (no max-tracking) ----
        float t1v[4][4], t2v[4][4];
        {
            const float* t1b = t1c + llb*66 + cc;
            #pragma unroll
            for (int reg = 0; reg < 4; ++reg)
                #pragma unroll
                for (int i = 0; i < 4; ++i)
                    t1v[reg][i] = t1b[reg*66 + i*16];
            const float* t2b = t2c + cc*67 + llb;
            #pragma unroll
            for (int i = 0; i < 4; ++i)
                #pragma unroll
                for (int reg = 0; reg < 4; ++reg)
                    t2v[reg][i] = t2b[i*1072 + reg];
        }
        #pragma unroll
        for (int reg = 0; reg < 4; ++reg){
            int ll = llb + reg;
            float ps = 0.f;
            #pragma unroll
            for (int i = 0; i < 4; ++i){
                float lvv = b2f(reg < 2 ? (unsigned short)lva[reg*4 + i]
                                        : (unsigned short)lvb[(reg-2)*4 + i]);
                float sv = (accs[i][reg] + t1v[reg][i] + t2v[reg][i]) * RS + lvv;
                float p = __builtin_amdgcn_exp2f(sv);
                ps += p;
                int rl = i*16 + cc;
                P[ll*64 + (((rl >> 3) ^ (ll & 7)) << 3) + (rl & 7)] = f2b(p);
            }
            ps += __shfl_xor(ps, 1); ps += __shfl_xor(ps, 2);
            ps += __shfl_xor(ps, 4); ps += __shfl_xor(ps, 8);
            l_run[reg] += ps;
        }

        // ---- PV ----
        __builtin_amdgcn_s_setprio(1);
        #pragma unroll
        for (int kh = 0; kh < 2; ++kh){
            int prow = w*16 + cc;
            bf8_t pf = *(const bf8_t*)&P[prow*64 + (((g + 4*kh) ^ (prow & 7)) << 3)];
            #pragma unroll
            for (int nf = 0; nf < 4; ++nf){
                int vr = nf*16 + cc;
                bf8_t vf = *(const bf8_t*)&vsq[vr*64 + (((g + 4*kh) ^ (vr & 7))*8)];
                ctx[nf] = __builtin_amdgcn_mfma_f32_16x16x32_bf16(pf, vf, ctx[nf], 0,0,0);
            }
        }
        __builtin_amdgcn_s_setprio(0);

        if (c8 < 7){
            __syncthreads();            // B1: PV done; drains K/DE loads
            stage_v(r0 + 64);
            __syncthreads();            // B2: drains V
        }
    }

    #pragma unroll
    for (int nf = 0; nf < 4; ++nf){
        #pragma unroll
        for (int reg = 0; reg < 4; ++reg){
            int ll = llb + reg;
            out[((size_t)b*Sv + l0 + ll)*HIDv + h*64 + nf*16 + cc] = ctx[nf][reg] / l_run[reg];
        }
    }
}

extern "C" void kernel_launch(void* const* d_in, const int* in_sizes, int n_in,
                              void* d_out, int out_size, void* d_ws, size_t ws_size,
                              hipStream_t stream)
{
    const float* hs   = (const float*)d_in[0];
    const float* mask = (const float*)d_in[1];
    const int*   cmat = (const int*)  d_in[2];
    const int*   wmat = (const int*)  d_in[3];
    const float* Wq   = (const float*)d_in[4];
    const float* bq   = (const float*)d_in[5];
    const float* Wk   = (const float*)d_in[6];
    const float* bk   = (const float*)d_in[7];
    const float* Wv   = (const float*)d_in[8];
    const float* bv   = (const float*)d_in[9];
    const float* de   = (const float*)d_in[10];
    const float* ce   = (const float*)d_in[11];
    const float* we   = (const float*)d_in[12];
    float* out = (float*)d_out;

    unsigned short* Xb   = (unsigned short*)d_ws;        // 8192*768
    unsigned short* Wb   = Xb   + 6291456;               // 2304*768
    unsigned short* deb  = Wb   + 1769472;               // 1023*64 (padded)
    unsigned short* qkb  = deb  + 65536;                 // 2*16*12*512*64
    unsigned short* vtb  = qkb  + 12582912;              // 16*12*64*512
    unsigned short* lvlt = vtb  + 6291456;               // 1024*256*16

    cvt_bf16<<<2048, 256, 0, stream>>>(hs, Xb, 1572864);
    cvt_w3<<<1728, 256, 0, stream>>>(Wq, Wk, Wv, Wb, 147456);
    cvt_bf16<<<64,   256, 0, stream>>>(de, deb, 16368);
    prep_bias_t<<<1024, 256, 0, stream>>>(cmat, wmat, mask, ce, we, lvlt);

    qkv_gemm<<<dim3(64, 18), 256, 0, stream>>>(Xb, Wb, bq, bk, bv, qkb, vtb);
    attn<<<1536, 256, 0, stream>>>(qkb, vtb, deb, lvlt, out);
}